// Round 1
// baseline (4764.590 us; speedup 1.0000x reference)
//
#include <hip/hip_runtime.h>

#define HD 1024
#define SQ 512
#define NHEAD 16
#define FFD 4096
#define NLAYER 12

typedef __attribute__((ext_vector_type(4))) float f32x4;
typedef __attribute__((ext_vector_type(8))) __bf16 bf16x8;

__device__ __forceinline__ short f2bf(float f) {
    union { float f; unsigned u; } v; v.f = f;
    unsigned r = v.u + 0x7fffu + ((v.u >> 16) & 1u);
    return (short)(r >> 16);
}
__device__ __forceinline__ float bf2f(short s) {
    union { unsigned u; float f; } v;
    v.u = ((unsigned)(unsigned short)s) << 16;
    return v.f;
}
__device__ __forceinline__ unsigned pk2(short a, short b) {
    return ((unsigned)(unsigned short)a) | (((unsigned)(unsigned short)b) << 16);
}
__device__ __forceinline__ void st16bf(short* dst, float4 a, float4 b, float4 c, float4 d) {
    uint4 u0, u1;
    u0.x = pk2(f2bf(a.x), f2bf(a.y)); u0.y = pk2(f2bf(a.z), f2bf(a.w));
    u0.z = pk2(f2bf(b.x), f2bf(b.y)); u0.w = pk2(f2bf(b.z), f2bf(b.w));
    u1.x = pk2(f2bf(c.x), f2bf(c.y)); u1.y = pk2(f2bf(c.z), f2bf(c.w));
    u1.z = pk2(f2bf(d.x), f2bf(d.y)); u1.w = pk2(f2bf(d.z), f2bf(d.w));
    *(uint4*)dst = u0; *(uint4*)(dst + 8) = u1;
}
__device__ __forceinline__ void stage16_raw(short* dst, const float* src) {
    float4 a = *(const float4*)(src);
    float4 b = *(const float4*)(src + 4);
    float4 c = *(const float4*)(src + 8);
    float4 d = *(const float4*)(src + 12);
    st16bf(dst, a, b, c, d);
}
__device__ __forceinline__ void stage32_raw(short* dst, const float* src) {
    stage16_raw(dst, src);
    stage16_raw(dst + 16, src + 16);
}
__device__ __forceinline__ float4 f4addscale(float4 a, float4 b, float s) {
    return make_float4((a.x + b.x) * s, (a.y + b.y) * s, (a.z + b.z) * s, (a.w + b.w) * s);
}
__device__ __forceinline__ float wave_sum(float x) {
    #pragma unroll
    for (int o = 32; o > 0; o >>= 1) x += __shfl_xor(x, o, 64);
    return x;
}
__device__ __forceinline__ float wave_max(float x) {
    #pragma unroll
    for (int o = 32; o > 0; o >>= 1) x = fmaxf(x, __shfl_xor(x, o, 64));
    return x;
}

// ---------------- embedding gather + LayerNorm * mask ----------------
__global__ __launch_bounds__(256) void embed_ln_kernel(
    const int* __restrict__ ids, const int* __restrict__ mask,
    const float* __restrict__ we, const float* __restrict__ s,
    const float* __restrict__ b, float* __restrict__ h)
{
    const int tok = blockIdx.x;
    const int tid = threadIdx.x, lane = tid & 63, w = tid >> 6;
    const float* row = we + (size_t)ids[tok] * HD;
    float4 v = *(const float4*)(row + tid * 4);
    __shared__ float red[8];
    float sm = wave_sum(v.x + v.y + v.z + v.w);
    float sq = wave_sum(v.x * v.x + v.y * v.y + v.z * v.z + v.w * v.w);
    if (!lane) { red[w] = sm; red[4 + w] = sq; }
    __syncthreads();
    float mean = (red[0] + red[1] + red[2] + red[3]) * (1.f / 1024.f);
    float var = (red[4] + red[5] + red[6] + red[7]) * (1.f / 1024.f) - mean * mean;
    float rs = rsqrtf(var + 1e-7f);
    float m = (float)mask[tok];
    float4 sv = *(const float4*)(s + tid * 4);
    float4 bv = *(const float4*)(b + tid * 4);
    float4 o;
    o.x = ((v.x - mean) * rs * sv.x + bv.x) * m;
    o.y = ((v.y - mean) * rs * sv.y + bv.y) * m;
    o.z = ((v.z - mean) * rs * sv.z + bv.z) * m;
    o.w = ((v.w - mean) * rs * sv.w + bv.w) * m;
    *(float4*)(h + (size_t)tok * HD + tid * 4) = o;
}

// ---------------- LayerNorm ----------------
__global__ __launch_bounds__(256) void ln_kernel(
    const float* __restrict__ x, const float* __restrict__ s,
    const float* __restrict__ b, float* __restrict__ o, float eps)
{
    const int row = blockIdx.x, tid = threadIdx.x, lane = tid & 63, w = tid >> 6;
    float4 v = *(const float4*)(x + (size_t)row * HD + tid * 4);
    __shared__ float red[8];
    float sm = wave_sum(v.x + v.y + v.z + v.w);
    float sq = wave_sum(v.x * v.x + v.y * v.y + v.z * v.z + v.w * v.w);
    if (!lane) { red[w] = sm; red[4 + w] = sq; }
    __syncthreads();
    float mean = (red[0] + red[1] + red[2] + red[3]) * (1.f / 1024.f);
    float var = (red[4] + red[5] + red[6] + red[7]) * (1.f / 1024.f) - mean * mean;
    float rs = rsqrtf(var + eps);
    float4 sv = *(const float4*)(s + tid * 4);
    float4 bv = *(const float4*)(b + tid * 4);
    float4 ov;
    ov.x = (v.x - mean) * rs * sv.x + bv.x;
    ov.y = (v.y - mean) * rs * sv.y + bv.y;
    ov.z = (v.z - mean) * rs * sv.z + bv.z;
    ov.w = (v.w - mean) * rs * sv.w + bv.w;
    *(float4*)(o + (size_t)row * HD + tid * 4) = ov;
}

// ---------------- GEMM: C[M,N] = (A[M,K] @ W[N,K]^T + bias)*alpha, gelu, +R ----------------
// flags: 1=bias, 2=residual, 4=gelu.  M,N,K multiples of 64.
__global__ __launch_bounds__(256) void gemm_kernel(
    const float* __restrict__ A, const float* __restrict__ W,
    const float* __restrict__ bias, const float* __restrict__ R,
    float* __restrict__ C, int M, int N, int K, int flags, float alpha)
{
    __shared__ __align__(16) short As[64 * 72];
    __shared__ __align__(16) short Bs[64 * 72];
    const int tid = threadIdx.x, lane = tid & 63, w = tid >> 6;
    const int quad = lane >> 4, l15 = lane & 15;
    const int n0 = blockIdx.x * 64, m0 = blockIdx.y * 64;
    const int srow = tid >> 2, scol = (tid & 3) << 4;
    const float* Ap = A + (size_t)(m0 + srow) * K + scol;
    const float* Wp = W + (size_t)(n0 + srow) * K + scol;
    f32x4 acc[4];
    #pragma unroll
    for (int i = 0; i < 4; i++) acc[i] = (f32x4){0.f, 0.f, 0.f, 0.f};

    for (int k0 = 0; k0 < K; k0 += 64) {
        float4 a0 = *(const float4*)(Ap + k0);
        float4 a1 = *(const float4*)(Ap + k0 + 4);
        float4 a2 = *(const float4*)(Ap + k0 + 8);
        float4 a3 = *(const float4*)(Ap + k0 + 12);
        float4 w0 = *(const float4*)(Wp + k0);
        float4 w1 = *(const float4*)(Wp + k0 + 4);
        float4 w2 = *(const float4*)(Wp + k0 + 8);
        float4 w3 = *(const float4*)(Wp + k0 + 12);
        __syncthreads();
        st16bf(&As[srow * 72 + scol], a0, a1, a2, a3);
        st16bf(&Bs[srow * 72 + scol], w0, w1, w2, w3);
        __syncthreads();
        #pragma unroll
        for (int ks = 0; ks < 2; ks++) {
            bf16x8 bfr = *(const bf16x8*)&Bs[(w * 16 + l15) * 72 + ks * 32 + quad * 8];
            #pragma unroll
            for (int mt = 0; mt < 4; mt++) {
                bf16x8 afr = *(const bf16x8*)&As[(mt * 16 + l15) * 72 + ks * 32 + quad * 8];
                acc[mt] = __builtin_amdgcn_mfma_f32_16x16x32_bf16(afr, bfr, acc[mt], 0, 0, 0);
            }
        }
    }
    const int n = n0 + w * 16 + l15;
    const float bv = (flags & 1) ? bias[n] : 0.f;
    #pragma unroll
    for (int mt = 0; mt < 4; mt++) {
        const int m = m0 + mt * 16 + quad * 4;
        #pragma unroll
        for (int r = 0; r < 4; r++) {
            float v = (acc[mt][r] + bv) * alpha;
            if (flags & 4) {
                float x = v;
                v = 0.5f * x * (1.f + tanhf(0.7978845608028654f * (x + 0.044715f * x * x * x)));
            }
            if (flags & 2) v += R[(size_t)(m + r) * N + n];
            C[(size_t)(m + r) * N + n] = v;
        }
    }
}

// ---------------- attention scores: qk + c2p + p2c ----------------
// grid (8 qtiles, 16 heads, 2 batch), 256 threads.
__global__ __launch_bounds__(256) void scores_kernel(
    const float* __restrict__ qkv, const float* __restrict__ qb,
    const float* __restrict__ pk, const float* __restrict__ pq,
    float* __restrict__ sc)
{
    __shared__ __align__(16) short s0[64 * 72];   // Q (ph1-2), K (ph3)
    __shared__ __align__(16) short s1[128 * 72];  // K / PK / PQ
    __shared__ float s2a[64 * 65];                // S1 accum + combine
    __shared__ short s2b[64 * 132];               // S2 / S3 (bf16)
    const int tid = threadIdx.x, lane = tid & 63, w = tid >> 6;
    const int quad = lane >> 4, l15 = lane & 15;
    const int qt = blockIdx.x, hh = blockIdx.y, b = blockIdx.z;
    const int q0 = qt * 64;
    const int srow = tid >> 2, scol = (tid & 3) << 4;
    const int prow = tid >> 1, pcol = (tid & 1) << 5;
    const int cqi = tid >> 2, ck0 = (tid & 3) << 4;
    const float* qsrc = qkv + (size_t)(b * SQ + q0 + srow) * (3 * HD) + hh * 192 + scol;
    const float* qbp = qb + hh * 64 + scol;
    const float iscale = 0.07216878364870322f;  // 1/sqrt(192)

    for (int kb = 0; kb < 8; kb++) {
        const int kbase = kb * 64;
        const int dbase = q0 - kbase + 449;
        const float* ksrc = qkv + (size_t)(b * SQ + kbase + srow) * (3 * HD) + hh * 192 + 64 + scol;
        __syncthreads();
        {   // stage Q -> s0, K -> s1 (rows 0..63)
            float4 a0 = *(const float4*)(qsrc);
            float4 a1 = *(const float4*)(qsrc + 4);
            float4 a2 = *(const float4*)(qsrc + 8);
            float4 a3 = *(const float4*)(qsrc + 12);
            float4 b0 = *(const float4*)(qbp);
            float4 b1 = *(const float4*)(qbp + 4);
            float4 b2 = *(const float4*)(qbp + 8);
            float4 b3 = *(const float4*)(qbp + 12);
            st16bf(&s0[srow * 72 + scol], f4addscale(a0, b0, iscale), f4addscale(a1, b1, iscale),
                   f4addscale(a2, b2, iscale), f4addscale(a3, b3, iscale));
            stage16_raw(&s1[srow * 72 + scol], ksrc);
        }
        __syncthreads();
        {   // S1 = Q @ K^T -> s2a (f32)
            f32x4 a1[4];
            #pragma unroll
            for (int i = 0; i < 4; i++) a1[i] = (f32x4){0.f, 0.f, 0.f, 0.f};
            #pragma unroll
            for (int ks = 0; ks < 2; ks++) {
                bf16x8 bfr = *(const bf16x8*)&s1[(w * 16 + l15) * 72 + ks * 32 + quad * 8];
                #pragma unroll
                for (int mt = 0; mt < 4; mt++) {
                    bf16x8 afr = *(const bf16x8*)&s0[(mt * 16 + l15) * 72 + ks * 32 + quad * 8];
                    a1[mt] = __builtin_amdgcn_mfma_f32_16x16x32_bf16(afr, bfr, a1[mt], 0, 0, 0);
                }
            }
            #pragma unroll
            for (int mt = 0; mt < 4; mt++)
                #pragma unroll
                for (int r = 0; r < 4; r++)
                    s2a[(mt * 16 + quad * 4 + r) * 65 + w * 16 + l15] = a1[mt][r];
        }
        __syncthreads();
        {   // stage PK window -> s1 (128 rows)
            int gr = dbase + prow; if (gr > 1023) gr = 1023;
            stage32_raw(&s1[prow * 72 + pcol], pk + (size_t)gr * HD + hh * 64 + pcol);
        }
        __syncthreads();
        {   // S2 = Q @ PK^T -> s2b (bf16)
            #pragma unroll
            for (int t2 = 0; t2 < 2; t2++) {
                const int nt = w + t2 * 4;
                f32x4 a2[4];
                #pragma unroll
                for (int i = 0; i < 4; i++) a2[i] = (f32x4){0.f, 0.f, 0.f, 0.f};
                #pragma unroll
                for (int ks = 0; ks < 2; ks++) {
                    bf16x8 bfr = *(const bf16x8*)&s1[(nt * 16 + l15) * 72 + ks * 32 + quad * 8];
                    #pragma unroll
                    for (int mt = 0; mt < 4; mt++) {
                        bf16x8 afr = *(const bf16x8*)&s0[(mt * 16 + l15) * 72 + ks * 32 + quad * 8];
                        a2[mt] = __builtin_amdgcn_mfma_f32_16x16x32_bf16(afr, bfr, a2[mt], 0, 0, 0);
                    }
                }
                #pragma unroll
                for (int mt = 0; mt < 4; mt++)
                    #pragma unroll
                    for (int r = 0; r < 4; r++)
                        s2b[(mt * 16 + quad * 4 + r) * 132 + nt * 16 + l15] = f2bf(a2[mt][r]);
            }
        }
        __syncthreads();
        {   // combine2: s2a[qi][kj] += S2[qi][qi-kj+63]
            #pragma unroll
            for (int j = 0; j < 16; j++) {
                const int kj = ck0 + j;
                s2a[cqi * 65 + kj] += bf2f(s2b[cqi * 132 + (cqi - kj + 63)]);
            }
        }
        __syncthreads();
        {   // stage K -> s0, PQ window -> s1
            stage16_raw(&s0[srow * 72 + scol], ksrc);
            int gr = dbase + prow; if (gr > 1023) gr = 1023;
            stage32_raw(&s1[prow * 72 + pcol], pq + (size_t)gr * HD + hh * 64 + pcol);
        }
        __syncthreads();
        {   // S3 = K @ PQ^T -> s2b (bf16)
            #pragma unroll
            for (int t2 = 0; t2 < 2; t2++) {
                const int nt = w + t2 * 4;
                f32x4 a3[4];
                #pragma unroll
                for (int i = 0; i < 4; i++) a3[i] = (f32x4){0.f, 0.f, 0.f, 0.f};
                #pragma unroll
                for (int ks = 0; ks < 2; ks++) {
                    bf16x8 bfr = *(const bf16x8*)&s1[(nt * 16 + l15) * 72 + ks * 32 + quad * 8];
                    #pragma unroll
                    for (int mt = 0; mt < 4; mt++) {
                        bf16x8 afr = *(const bf16x8*)&s0[(mt * 16 + l15) * 72 + ks * 32 + quad * 8];
                        a3[mt] = __builtin_amdgcn_mfma_f32_16x16x32_bf16(afr, bfr, a3[mt], 0, 0, 0);
                    }
                }
                #pragma unroll
                for (int mt = 0; mt < 4; mt++)
                    #pragma unroll
                    for (int r = 0; r < 4; r++)
                        s2b[(mt * 16 + quad * 4 + r) * 132 + nt * 16 + l15] = f2bf(a3[mt][r]);
            }
        }
        __syncthreads();
        {   // combine3 + global write
            float* outp = sc + ((size_t)((b * NHEAD + hh) * SQ + q0 + cqi)) * SQ + kbase;
            #pragma unroll
            for (int j = 0; j < 16; j++) {
                const int kj = ck0 + j;
                outp[kj] = s2a[cqi * 65 + kj] + bf2f(s2b[kj * 132 + (cqi - kj + 63)]);
            }
        }
    }
}

// ---------------- softmax (+mask) -> bf16 probs ----------------
__global__ __launch_bounds__(256) void softmax_kernel(
    const float* __restrict__ sc, const int* __restrict__ mask,
    unsigned short* __restrict__ probs)
{
    const int tid = threadIdx.x, lane = tid & 63, w = tid >> 6;
    const int row = blockIdx.x * 4 + w;   // (b*16+h)*512 + qi
    const int b = row >> 13;
    const int qi = row & 511;
    const float* x = sc + (size_t)row * SQ + lane * 8;
    float4 v1 = *(const float4*)x;
    float4 v2 = *(const float4*)(x + 4);
    float xv[8] = {v1.x, v1.y, v1.z, v1.w, v2.x, v2.y, v2.z, v2.w};
    const float mq = (float)mask[b * SQ + qi];
    const int* mrow = mask + b * SQ + lane * 8;
    float mk[8];
    #pragma unroll
    for (int j = 0; j < 8; j++) {
        mk[j] = (float)mrow[j];
        xv[j] = mk[j] > 0.f ? xv[j] : -1e9f;
    }
    float mx = xv[0];
    #pragma unroll
    for (int j = 1; j < 8; j++) mx = fmaxf(mx, xv[j]);
    mx = wave_max(mx);
    float e[8], sm = 0.f;
    #pragma unroll
    for (int j = 0; j < 8; j++) { e[j] = __expf(xv[j] - mx); sm += e[j]; }
    sm = wave_sum(sm);
    const float inv = 1.f / sm;
    uint4 u;
    short p[8];
    #pragma unroll
    for (int j = 0; j < 8; j++) p[j] = f2bf(e[j] * inv * mk[j] * mq);
    u.x = pk2(p[0], p[1]); u.y = pk2(p[2], p[3]); u.z = pk2(p[4], p[5]); u.w = pk2(p[6], p[7]);
    *(uint4*)(probs + (size_t)row * SQ + lane * 8) = u;
}

// ---------------- PV: ctx = probs @ V ----------------
__global__ __launch_bounds__(256) void pv_kernel(
    const unsigned short* __restrict__ probs, const float* __restrict__ qkv,
    const float* __restrict__ vb, float* __restrict__ ctx)
{
    __shared__ __align__(16) short Ps[64 * 40];
    __shared__ __align__(16) short Vs[64 * 40];
    const int tid = threadIdx.x, lane = tid & 63, w = tid >> 6;
    const int quad = lane >> 4, l15 = lane & 15;
    const int qt = blockIdx.x, hh = blockIdx.y, b = blockIdx.z;
    const int q0 = qt * 64;
    const int prow = tid >> 2, pcol = (tid & 3) << 3;
    const int vkj = tid & 31, vd0 = (tid >> 5) << 3;
    const unsigned short* pbase = probs + ((size_t)((b * NHEAD + hh) * SQ + q0 + prow)) * SQ + pcol;
    const float* vbase = qkv + (size_t)(b * SQ + vkj) * (3 * HD) + hh * 192 + 128 + vd0;
    float4 vb0 = *(const float4*)(vb + hh * 64 + vd0);
    float4 vb1 = *(const float4*)(vb + hh * 64 + vd0 + 4);
    f32x4 acc[4];
    #pragma unroll
    for (int i = 0; i < 4; i++) acc[i] = (f32x4){0.f, 0.f, 0.f, 0.f};
    for (int kb = 0; kb < 16; kb++) {
        __syncthreads();
        *(uint4*)&Ps[prow * 40 + pcol] = *(const uint4*)(pbase + kb * 32);
        const float* vs = vbase + (size_t)kb * 32 * (3 * HD);
        float4 v0 = *(const float4*)vs;
        float4 v1 = *(const float4*)(vs + 4);
        Vs[(vd0 + 0) * 40 + vkj] = f2bf(v0.x + vb0.x);
        Vs[(vd0 + 1) * 40 + vkj] = f2bf(v0.y + vb0.y);
        Vs[(vd0 + 2) * 40 + vkj] = f2bf(v0.z + vb0.z);
        Vs[(vd0 + 3) * 40 + vkj] = f2bf(v0.w + vb0.w);
        Vs[(vd0 + 4) * 40 + vkj] = f2bf(v1.x + vb1.x);
        Vs[(vd0 + 5) * 40 + vkj] = f2bf(v1.y + vb1.y);
        Vs[(vd0 + 6) * 40 + vkj] = f2bf(v1.z + vb1.z);
        Vs[(vd0 + 7) * 40 + vkj] = f2bf(v1.w + vb1.w);
        __syncthreads();
        bf16x8 bfr = *(const bf16x8*)&Vs[(w * 16 + l15) * 40 + quad * 8];
        #pragma unroll
        for (int mt = 0; mt < 4; mt++) {
            bf16x8 afr = *(const bf16x8*)&Ps[(mt * 16 + l15) * 40 + quad * 8];
            acc[mt] = __builtin_amdgcn_mfma_f32_16x16x32_bf16(afr, bfr, acc[mt], 0, 0, 0);
        }
    }
    #pragma unroll
    for (int mt = 0; mt < 4; mt++)
        #pragma unroll
        for (int r = 0; r < 4; r++)
            ctx[(size_t)(b * SQ + q0 + mt * 16 + quad * 4 + r) * HD + hh * 64 + w * 16 + l15] = acc[mt][r];
}

// ---------------- final head: LN(cls, eps=1e-5) @ out_w^T + out_b ----------------
__global__ __launch_bounds__(256) void head_kernel(
    const float* __restrict__ h, const float* __restrict__ s,
    const float* __restrict__ b, const float* __restrict__ ow,
    const float* __restrict__ ob, float* __restrict__ out)
{
    const int bb = blockIdx.x, tid = threadIdx.x, lane = tid & 63, w = tid >> 6;
    const float* x = h + (size_t)bb * SQ * HD;
    float4 v = *(const float4*)(x + tid * 4);
    __shared__ float red[8];
    float sm = wave_sum(v.x + v.y + v.z + v.w);
    float sq = wave_sum(v.x * v.x + v.y * v.y + v.z * v.z + v.w * v.w);
    if (!lane) { red[w] = sm; red[4 + w] = sq; }
    __syncthreads();
    float mean = (red[0] + red[1] + red[2] + red[3]) * (1.f / 1024.f);
    float var = (red[4] + red[5] + red[6] + red[7]) * (1.f / 1024.f) - mean * mean;
    float rs = rsqrtf(var + 1e-5f);
    float4 sv = *(const float4*)(s + tid * 4);
    float4 bv = *(const float4*)(b + tid * 4);
    float4 ov = *(const float4*)(ow + tid * 4);
    float d = ((v.x - mean) * rs * sv.x + bv.x) * ov.x
            + ((v.y - mean) * rs * sv.y + bv.y) * ov.y
            + ((v.z - mean) * rs * sv.z + bv.z) * ov.z
            + ((v.w - mean) * rs * sv.w + bv.w) * ov.w;
    d = wave_sum(d);
    __syncthreads();
    if (!lane) red[w] = d;
    __syncthreads();
    if (tid == 0) out[bb] = red[0] + red[1] + red[2] + red[3] + ob[0];
}

extern "C" void kernel_launch(void* const* d_in, const int* in_sizes, int n_in,
                              void* d_out, int out_size, void* d_ws, size_t ws_size,
                              hipStream_t stream) {
    (void)in_sizes; (void)n_in; (void)out_size; (void)ws_size;
    const int* ids        = (const int*)d_in[0];
    const int* mask       = (const int*)d_in[1];
    const float* word_emb = (const float*)d_in[3];
    const float* emb_ln_s = (const float*)d_in[4];
    const float* emb_ln_b = (const float*)d_in[5];
    const float* rel_emb  = (const float*)d_in[6];
    const float* in_w     = (const float*)d_in[7];
    const float* q_bias   = (const float*)d_in[8];
    const float* v_bias   = (const float*)d_in[9];
    const float* pos_k_w  = (const float*)d_in[10];
    const float* pos_q_w  = (const float*)d_in[11];
    const float* pos_q_b  = (const float*)d_in[12];
    const float* attn_o_w = (const float*)d_in[13];
    const float* attn_o_b = (const float*)d_in[14];
    const float* ln1_s    = (const float*)d_in[15];
    const float* ln1_b    = (const float*)d_in[16];
    const float* ffn_w1   = (const float*)d_in[17];
    const float* ffn_b1   = (const float*)d_in[18];
    const float* ffn_w2   = (const float*)d_in[19];
    const float* ffn_b2   = (const float*)d_in[20];
    const float* ln2_s    = (const float*)d_in[21];
    const float* ln2_b    = (const float*)d_in[22];
    const float* head_ln_s = (const float*)d_in[23];
    const float* head_ln_b = (const float*)d_in[24];
    const float* out_w    = (const float*)d_in[25];
    const float* out_b    = (const float*)d_in[26];
    float* out = (float*)d_out;
    float* ws = (float*)d_ws;

    const size_t M1 = 1024 * 1024;
    float* h    = ws;
    float* t    = ws + M1;
    float* qkvb = ws + 2 * M1;   // 1024 x 3072
    float* pkb  = ws + 5 * M1;   // 1024 x 1024
    float* pqb  = ws + 6 * M1;   // 1024 x 1024
    float* ctx  = ws + 7 * M1;   // 1024 x 1024
    float* ffb  = ws + 8 * M1;   // 1024 x 4096
    float* scb  = ws + 12 * M1;  // 32 x 512 x 512 f32
    unsigned short* probs = (unsigned short*)(ws + 20 * M1);  // 32 x 512 x 512 bf16
    const float SCI = 0.07216878364870322f;  // 1/sqrt(192)

    embed_ln_kernel<<<dim3(1024), dim3(256), 0, stream>>>(ids, mask, word_emb, emb_ln_s, emb_ln_b, h);

    for (int l = 0; l < NLAYER; l++) {
        gemm_kernel<<<dim3(48, 16), dim3(256), 0, stream>>>(
            h, in_w + (size_t)l * 3 * M1, nullptr, nullptr, qkvb, 1024, 3072, 1024, 0, 1.f);
        gemm_kernel<<<dim3(16, 16), dim3(256), 0, stream>>>(
            rel_emb, pos_k_w + (size_t)l * M1, nullptr, nullptr, pkb, 1024, 1024, 1024, 0, 1.f);
        gemm_kernel<<<dim3(16, 16), dim3(256), 0, stream>>>(
            rel_emb, pos_q_w + (size_t)l * M1, pos_q_b + l * 1024, nullptr, pqb, 1024, 1024, 1024, 1, SCI);
        scores_kernel<<<dim3(8, 16, 2), dim3(256), 0, stream>>>(
            qkvb, q_bias + l * 1024, pkb, pqb, scb);
        softmax_kernel<<<dim3(4096), dim3(256), 0, stream>>>(scb, mask, probs);
        pv_kernel<<<dim3(8, 16, 2), dim3(256), 0, stream>>>(
            probs, qkvb, v_bias + l * 1024, ctx);
        gemm_kernel<<<dim3(16, 16), dim3(256), 0, stream>>>(
            ctx, attn_o_w + (size_t)l * M1, attn_o_b + l * 1024, h, t, 1024, 1024, 1024, 3, 1.f);
        ln_kernel<<<dim3(1024), dim3(256), 0, stream>>>(t, ln1_s + l * 1024, ln1_b + l * 1024, h, 1e-7f);
        gemm_kernel<<<dim3(64, 16), dim3(256), 0, stream>>>(
            h, ffn_w1 + (size_t)l * 4 * M1, ffn_b1 + l * 4096, nullptr, ffb, 1024, 4096, 1024, 5, 1.f);
        gemm_kernel<<<dim3(16, 16), dim3(256), 0, stream>>>(
            ffb, ffn_w2 + (size_t)l * 4 * M1, ffn_b2 + l * 1024, h, t, 1024, 1024, 4096, 3, 1.f);
        ln_kernel<<<dim3(1024), dim3(256), 0, stream>>>(t, ln2_s + l * 1024, ln2_b + l * 1024, h, 1e-7f);
    }
    head_kernel<<<dim3(2), dim3(256), 0, stream>>>(h, head_ln_s, head_ln_b, out_w, out_b, out);
}